// Round 15
// baseline (289.885 us; speedup 1.0000x reference)
//
#include <hip/hip_runtime.h>
#include <hip/hip_bf16.h>

// ArcFace fused: cos = emb @ (w/||w||), margin at target label, softmax over batch axis.
// N=512, D=512, C=100000 (= 3125*32 exact -> BC=32, zero guards), S=1.
//
// ROUND 15: r9..r14 showed a ~1900cy/step invariant K-loop cost, independent of
// occupancy (40% vs 75% identical), barriers, rings, residency. The never-varied
// knob is the STEP COUNT itself (NSTEP=16 since r3). This round: BK 32->64 ->
// NSTEP=8, halving the per-step envelope count (vmcnt+barrier+ds_read+lgkm+stage).
// Same validated schedule as r12/r14: B staged via global_load_lds (triple-buffer,
// 2-step lead, counted vmcnt(1), drain only at last step); A direct from L2 with
// ring-2; one barrier per step.
//
//   label_scan : tgt one-hot -> labels[512]        (~35us, BW floor)
//   prep_afrag : emb f32 -> bf16 A-fragments       (512 KB, L2-resident)
//   wt_kernel  : w f32 -> bf16 B-fragments + rsqrt col norms (~50us)
//   arcface_main: 1024 thr = 16 waves, wave = 32 rows x 32 cols, acc[2][2]=16 AGPR,
//     A-ring a2[2][4] (64 VGPR). Per step (BK=64): [stager wv<4: vmcnt(1) | others:
//     vmcnt(0)] -> s_barrier -> ds_read B x4 -> issue A(K+1) x4 -> lgkmcnt(0) ->
//     stage B(K+2) -> 8 MFMA. Fixed-shift softmax epilogue (validated r9).

static constexpr int DIM    = 512;
static constexpr int NROWS  = 512;
static constexpr int NCLS   = 100000;
static constexpr int BC     = 32;
static constexpr int BK     = 64;              // K per step (2 MFMA-K)
static constexpr int NSTEP  = DIM / BK;        // 8
static constexpr int MT     = NROWS / 16;      // 32
static constexpr int NBLK   = NCLS / BC;       // 3125 exact

static constexpr float COS_M = 0.87758256189037271611f;  // cos(0.5)
static constexpr float SIN_M = 0.47942553860420300027f;  // sin(0.5)
static constexpr float SCALE = 64.0f;
static constexpr float SHIFT = 20.0f;          // fixed softmax shift

typedef __attribute__((ext_vector_type(8))) short bf16x8;
typedef __attribute__((ext_vector_type(4))) float f32x4;

#define MFMA16(A, B, C) __builtin_amdgcn_mfma_f32_16x16x32_bf16((A), (B), (C), 0, 0, 0)

__device__ __forceinline__ unsigned short f2bf(float f) {
  union { float f; unsigned u; } v; v.f = f;
  unsigned u = v.u;
  return (unsigned short)((u + 0x7FFFu + ((u >> 16) & 1u)) >> 16);
}

// ---------------------------------------------------------------------------
__global__ __launch_bounds__(1024)
void label_scan(const float* __restrict__ tgt, int* __restrict__ labels) {
  const int row = blockIdx.x;
  const int nq = NCLS / 4;
  const int q0 = blockIdx.y * (nq / 4);
  const int q1 = (blockIdx.y == 3) ? nq : q0 + (nq / 4);
  const float4* rp = reinterpret_cast<const float4*>(tgt + (size_t)row * NCLS);
  int found = -1;
  for (int c4 = q0 + threadIdx.x; c4 < q1; c4 += 1024) {
    const float4 v = rp[c4];
    if (v.x > 0.5f) found = c4 * 4 + 0;
    if (v.y > 0.5f) found = c4 * 4 + 1;
    if (v.z > 0.5f) found = c4 * 4 + 2;
    if (v.w > 0.5f) found = c4 * 4 + 3;
  }
  if (found >= 0) labels[row] = found;   // exactly one writer per row
}

// ---------------------------------------------------------------------------
__global__ void prep_afrag(const float* __restrict__ emb,
                           unsigned short* __restrict__ afrag) {
  const int idx = blockIdx.x * blockDim.x + threadIdx.x;  // 0..32767
  const int l  = idx & 63;
  const int mt = (idx >> 6) & 31;
  const int ks = idx >> 11;            // 32-k group
  const int row = mt * 16 + (l & 15);
  const int k0  = ks * 32 + (l >> 4) * 8;

  unsigned short t[8];
#pragma unroll
  for (int j = 0; j < 8; ++j) t[j] = f2bf(emb[row * DIM + k0 + j]);

  uint4 v;
  v.x = (unsigned)t[0] | ((unsigned)t[1] << 16);
  v.y = (unsigned)t[2] | ((unsigned)t[3] << 16);
  v.z = (unsigned)t[4] | ((unsigned)t[5] << 16);
  v.w = (unsigned)t[6] | ((unsigned)t[7] << 16);
  *reinterpret_cast<uint4*>(&afrag[(size_t)idx * 8]) = v;
}

// ---------------------------------------------------------------------------
// wt_kernel: bfrag fragment index = cb*32 + p*2 + j  (p = 32-k group, j = col half)
// -> for BK=64 main step KS, the 4 frags are contiguous at cb*32 + KS*4 .. +3.
// ---------------------------------------------------------------------------
__global__ __launch_bounds__(256)
void wt_kernel(const float* __restrict__ w,
               unsigned short* __restrict__ bfrag,
               float* __restrict__ rnorm) {
  __shared__ float S[32][33];
  __shared__ float NRM[32][32];

  const int t  = threadIdx.x;
  const int cb = blockIdx.x;
  const int c0 = cb * 32;

  const int rk = t >> 3;
  const int rc = (t & 7) * 4;

  float4 nrm4 = {0.f, 0.f, 0.f, 0.f};

  for (int p = 0; p < 16; ++p) {
    const float4 v = *reinterpret_cast<const float4*>(
        w + (size_t)(p * 32 + rk) * NCLS + c0 + rc);
    nrm4.x += v.x * v.x; nrm4.y += v.y * v.y;
    nrm4.z += v.z * v.z; nrm4.w += v.w * v.w;
    __syncthreads();
    *reinterpret_cast<float4*>(&S[rk][rc]) = v;
    __syncthreads();

    if (t < 128) {
      const int l2 = t & 63;
      const int j  = t >> 6;
      const int col = j * 16 + (l2 & 15);
      const int kb  = (l2 >> 4) * 8;
      uint4 pk;
      pk.x = (unsigned)f2bf(S[kb + 0][col]) | ((unsigned)f2bf(S[kb + 1][col]) << 16);
      pk.y = (unsigned)f2bf(S[kb + 2][col]) | ((unsigned)f2bf(S[kb + 3][col]) << 16);
      pk.z = (unsigned)f2bf(S[kb + 4][col]) | ((unsigned)f2bf(S[kb + 5][col]) << 16);
      pk.w = (unsigned)f2bf(S[kb + 6][col]) | ((unsigned)f2bf(S[kb + 7][col]) << 16);
      *reinterpret_cast<uint4*>(
          &bfrag[(((size_t)(cb * 16 + p) * 2 + j) * 64 + l2) * 8]) = pk;
    }
  }

  NRM[rk][rc + 0] = nrm4.x;
  NRM[rk][rc + 1] = nrm4.y;
  NRM[rk][rc + 2] = nrm4.z;
  NRM[rk][rc + 3] = nrm4.w;
  __syncthreads();
  if (t < 32) {
    float s = 0.f;
#pragma unroll
    for (int g = 0; g < 32; ++g) s += NRM[g][t];
    rnorm[c0 + t] = rsqrtf(fmaxf(s, 1e-20f));
  }
}

// ---------------------------------------------------------------------------
// Main kernel. 1024 threads = 16 waves; wave wv owns rows [wv*32, wv*32+32)
// x the block's 32 columns. BK=64 -> 8 steps.
// ---------------------------------------------------------------------------
__global__ __launch_bounds__(1024, 4)
void arcface_main(const unsigned short* __restrict__ bfrag,
                  const unsigned short* __restrict__ afrag,
                  const float* __restrict__ rnorm,
                  const int* __restrict__ labels,
                  float* __restrict__ out) {
  __shared__ alignas(16) unsigned short B3[3][2048];   // 3 x 4 KB B step-frags
  __shared__ float red[16][BC];
  __shared__ float colv[BC];

  const int tid = threadIdx.x;
  const int wv  = tid >> 6;        // 0..15
  const int l   = tid & 63;
  const int lh  = l >> 4;
  const int ll  = l & 15;
  const int c0  = blockIdx.x * BC;

  const char* bfb  = (const char*)bfrag + (size_t)blockIdx.x * 32768;
  const char* aptr = (const char*)afrag + (size_t)(wv * 2) * 1024 + (size_t)l * 16;
  char* b3b = (char*)&B3[0][0];

  f32x4 acc[2][2] = {};
  bf16x8 a2[2][4];   // A ring: [step&1][kk*2 + mt]

  // stage the 4 B frags (4 KB) for step KS into buffer BUF (waves 0-3)
#define STAGE(KS, BUF)                                                          \
  if (wv < 4) {                                                                 \
    const int dof = __builtin_amdgcn_readfirstlane((BUF) * 4096 + wv * 1024);   \
    __builtin_amdgcn_global_load_lds(                                           \
        (const __attribute__((address_space(1))) void*)                        \
            (bfb + (size_t)((KS) * 4 + wv) * 1024 + (size_t)l * 16),            \
        (__attribute__((address_space(3))) void*)(b3b + dof), 16, 0, 0);        \
  }

  // A frags for step KS (k-groups 2KS, 2KS+1; m-tiles wv*2, wv*2+1)
#define LOADA(KS, RING)                                                         \
  {                                                                             \
    a2[RING][0] = *reinterpret_cast<const bf16x8*>(aptr + (size_t)(2 * (KS) + 0) * 32768);          \
    a2[RING][1] = *reinterpret_cast<const bf16x8*>(aptr + (size_t)(2 * (KS) + 0) * 32768 + 1024);   \
    a2[RING][2] = *reinterpret_cast<const bf16x8*>(aptr + (size_t)(2 * (KS) + 1) * 32768);          \
    a2[RING][3] = *reinterpret_cast<const bf16x8*>(aptr + (size_t)(2 * (KS) + 1) * 32768 + 1024);   \
  }

  // prologue queue (stager): B0, A0 x4, B1 -> step-0 wait vmcnt(1) keeps B1 flying
  STAGE(0, 0)
  LOADA(0, 0)
  STAGE(1, 1)

  // STEP(K): wait(B(K)+A(K) landed; B(K+1) flying) -> barrier -> ds_read B x4 ->
  // issue A(K+1) -> lgkm(0) -> stage B(K+2) -> 8 MFMA (2-chain per acc).
#define STEP(KS, VMS)                                                           \
  {                                                                             \
    if (wv < 4) { asm volatile("s_waitcnt vmcnt(" #VMS ")" ::: "memory"); }     \
    else        { asm volatile("s_waitcnt vmcnt(0)" ::: "memory"); }            \
    __builtin_amdgcn_s_barrier();                                               \
    __builtin_amdgcn_sched_barrier(0);                                          \
    bf16x8 b00 = *reinterpret_cast<const bf16x8*>(b3b + ((KS) % 3) * 4096 + 0 * 1024 + l * 16); \
    bf16x8 b01 = *reinterpret_cast<const bf16x8*>(b3b + ((KS) % 3) * 4096 + 1 * 1024 + l * 16); \
    bf16x8 b10 = *reinterpret_cast<const bf16x8*>(b3b + ((KS) % 3) * 4096 + 2 * 1024 + l * 16); \
    bf16x8 b11 = *reinterpret_cast<const bf16x8*>(b3b + ((KS) % 3) * 4096 + 3 * 1024 + l * 16); \
    if ((KS) + 1 < NSTEP) LOADA((KS) + 1, ((KS) + 1) & 1)                       \
    asm volatile("s_waitcnt lgkmcnt(0)" ::: "memory");                          \
    __builtin_amdgcn_sched_barrier(0);                                          \
    if ((KS) + 2 < NSTEP) STAGE((KS) + 2, ((KS) + 2) % 3)                       \
    acc[0][0] = MFMA16(a2[(KS) & 1][0], b00, acc[0][0]);                        \
    acc[0][1] = MFMA16(a2[(KS) & 1][0], b01, acc[0][1]);                        \
    acc[1][0] = MFMA16(a2[(KS) & 1][1], b00, acc[1][0]);                        \
    acc[1][1] = MFMA16(a2[(KS) & 1][1], b01, acc[1][1]);                        \
    acc[0][0] = MFMA16(a2[(KS) & 1][2], b10, acc[0][0]);                        \
    acc[0][1] = MFMA16(a2[(KS) & 1][2], b11, acc[0][1]);                        \
    acc[1][0] = MFMA16(a2[(KS) & 1][3], b10, acc[1][0]);                        \
    acc[1][1] = MFMA16(a2[(KS) & 1][3], b11, acc[1][1]);                        \
  }

  STEP(0, 1)  STEP(1, 1)  STEP(2, 1)  STEP(3, 1)
  STEP(4, 1)  STEP(5, 1)  STEP(6, 1)  STEP(7, 0)
#undef STEP
#undef STAGE
#undef LOADA

  // ---- epilogue (fixed-shift softmax; labels are global col ids)
  float rn[2];
#pragma unroll
  for (int j = 0; j < 2; ++j) rn[j] = rnorm[c0 + j * 16 + ll];

  int lab[2][4];
#pragma unroll
  for (int i = 0; i < 2; ++i)
#pragma unroll
    for (int q = 0; q < 4; ++q)
      lab[i][q] = labels[wv * 32 + i * 16 + lh * 4 + q];

  float sme[2] = {0.f, 0.f};
#pragma unroll
  for (int j = 0; j < 2; ++j) {
    const int cj = c0 + j * 16 + ll;
#pragma unroll
    for (int i = 0; i < 2; ++i) {
#pragma unroll
      for (int q = 0; q < 4; ++q) {
        float cosv = acc[i][j][q] * rn[j];
        cosv = fminf(fmaxf(cosv, -1.f), 1.f);
        float lg;
        if (lab[i][q] == cj) {
          const float s = sqrtf(fmaxf(1.f - cosv * cosv, 0.f));
          lg = cosv * COS_M - s * SIN_M;
        } else {
          lg = cosv;
        }
        const float e = __expf(lg * SCALE - SHIFT);
        acc[i][j][q] = e;
        sme[j] += e;
      }
    }
  }

  // column sums: lanes sharing a column differ in lh (xor 16/32), then 16 waves
#pragma unroll
  for (int j = 0; j < 2; ++j) {
    sme[j] += __shfl_xor(sme[j], 16, 64);
    sme[j] += __shfl_xor(sme[j], 32, 64);
  }
  __syncthreads();
  if (l < 16) {
#pragma unroll
    for (int j = 0; j < 2; ++j) red[wv][j * 16 + l] = sme[j];
  }
  __syncthreads();
  if (tid < BC) {
    float s = 0.f;
#pragma unroll
    for (int v2 = 0; v2 < 16; ++v2) s += red[v2][tid];
    colv[tid] = s;
  }
  __syncthreads();

  float rs[2];
#pragma unroll
  for (int j = 0; j < 2; ++j) rs[j] = 1.0f / colv[j * 16 + ll];

#pragma unroll
  for (int j = 0; j < 2; ++j) {
    const int cj = c0 + j * 16 + ll;
#pragma unroll
    for (int i = 0; i < 2; ++i) {
#pragma unroll
      for (int q = 0; q < 4; ++q) {
        const int row = wv * 32 + i * 16 + lh * 4 + q;
        out[(size_t)row * NCLS + cj] = acc[i][j][q] * rs[j];
      }
    }
  }
}

extern "C" void kernel_launch(void* const* d_in, const int* in_sizes, int n_in,
                              void* d_out, int out_size, void* d_ws, size_t ws_size,
                              hipStream_t stream) {
  const float* emb = (const float*)d_in[0];   // [512][512]
  const float* w   = (const float*)d_in[1];   // [512][100000]
  const float* tgt = (const float*)d_in[2];   // [512][100000]
  float* out = (float*)d_out;                 // [512][100000]

  char* ws = (char*)d_ws;
  int* labels           = (int*)ws;                              // 2 KB
  unsigned short* afrag = (unsigned short*)(ws + 4096);          // 512 KB
  float* rnorm          = (float*)(ws + (1u << 20));             // 400 KB
  unsigned short* bfrag = (unsigned short*)(ws + (2u << 20));    // 100 MB

  label_scan<<<dim3(NROWS, 4), 1024, 0, stream>>>(tgt, labels);
  prep_afrag<<<64, 512, 0, stream>>>(emb, afrag);
  wt_kernel<<<NBLK, 256, 0, stream>>>(w, bfrag, rnorm);
  arcface_main<<<NBLK, 1024, 0, stream>>>(bfrag, afrag, rnorm, labels, out);
}